// Round 3
// baseline (41.333 us; speedup 1.0000x reference)
//
#include <hip/hip_runtime.h>

// KnnLinearFixModel: B=512, K=64, D=1024, L=8, 20 SGD steps.
// W_t = c^t*W0 + A_t*X (c=1-LR*WD) -> only G=X*X^T, M0=X*W0^T, q=X*e, p0=W0*e
// are needed; the 20-step loop runs on 64x(8..16) matrices on-chip.
// R3: 512-thread blocks (8 waves) -> 16 waves/CU (grid was capping occupancy
// at 8 waves/CU); BK=128 chunks halve barrier count and per-thread staging.

#define BB 512
#define KK 64
#define DD 1024
#define LL 8
#define NSTEPS 20
#define BKC 128              // D-columns per staged chunk
#define NCH (DD / BKC)       // 8 chunks
#define XST 136              // X/P LDS row stride in shorts (128 + 8 pad)

typedef __attribute__((ext_vector_type(8))) short bf16x8;
typedef __attribute__((ext_vector_type(4))) float f32x4;

__device__ __forceinline__ short f2bf(float f) {
    // round-to-nearest-even f32 -> bf16 (finite inputs only)
    unsigned u = __float_as_uint(f);
    unsigned r = (u + 0x7FFFu + ((u >> 16) & 1u)) >> 16;
    return (short)r;
}

struct Chunk {
    float4 x0, x1, x2, x3;  // X rows xr, xr+16, xr+32, xr+48 (16B each)
    float4 p;               // P row xr (W0 rows 0-7, e at row 8, zeros 9-15)
};

__global__ __launch_bounds__(512, 4)
void knn_linear_fix_kernel(const float* __restrict__ demo,   // [B,K,D]
                           const float* __restrict__ emb,    // [B,D]
                           const float* __restrict__ W0,     // [B,L,D]
                           const float* __restrict__ b0,     // [B,L]
                           const int*   __restrict__ labels, // [B,K]
                           float* __restrict__ out)          // [B,L]
{
    const int b    = blockIdx.x;
    const int t    = threadIdx.x;
    const int lane = t & 63;
    const int wid  = t >> 6;          // wave id 0..7
    const int lg   = lane >> 4;       // lane group 0..3
    const int lr   = lane & 15;       // row (A) / col (B, C/D) index
    const int rt   = wid & 3;         // G row-tile owned by this wave
    const int cp   = wid >> 2;        // G col-pair: tiles 2cp, 2cp+1

    const float LR  = 1e-4f;
    const float WD  = 0.01f;
    const float LRS = LR * (2.0f / (float)(KK * LL)); // 3.90625e-7
    const float CD  = 1.0f - LR * WD;

    __shared__ short Xs[64 * XST];  // X chunk, bf16 (17.4 KB)
    __shared__ short Ps[16 * XST];  // W0 rows 0-7, e row 8, zeros 9-15 (4.4 KB)
    __shared__ short Gs[64 * 72];   // G = X X^T, bf16 (stride 72: 144B rows)
    __shared__ short Ss[16 * 72];   // S^T: [col][k-row], bf16
    __shared__ float Ms[64 * 16];   // M: cols 0-7 = M0 = X W0^T, col 8 = q = X.e
    __shared__ float red[256];      // cross-wave reduction buffer
    __shared__ float p0_s[16];      // p0 = W0 . e
    __shared__ int   lab_s[64];

    const float* Xg = demo + (size_t)b * (KK * DD);
    const float* Wg = W0   + (size_t)b * (LL * DD);
    const float* eg = emb  + (size_t)b * DD;

    const int xr = t >> 5;          // staging row 0..15
    const int xc = (t & 31) * 4;    // staging col (floats) 0..124

#define LOADX(buf, CH) do {                                                      \
        const int dk = (CH) * BKC;                                               \
        (buf).x0 = *(const float4*)(Xg + (size_t)(xr     ) * DD + dk + xc);      \
        (buf).x1 = *(const float4*)(Xg + (size_t)(xr + 16) * DD + dk + xc);      \
        (buf).x2 = *(const float4*)(Xg + (size_t)(xr + 32) * DD + dk + xc);      \
        (buf).x3 = *(const float4*)(Xg + (size_t)(xr + 48) * DD + dk + xc);      \
        if (xr < 8)       (buf).p = *(const float4*)(Wg + (size_t)xr * DD + dk + xc); \
        else if (xr == 8) (buf).p = *(const float4*)(eg + dk + xc);              \
        else              (buf).p = make_float4(0.f, 0.f, 0.f, 0.f);             \
    } while (0)

#define STOREC(buf) do {                                                         \
        short4 h;                                                                \
        h.x = f2bf((buf).x0.x); h.y = f2bf((buf).x0.y);                          \
        h.z = f2bf((buf).x0.z); h.w = f2bf((buf).x0.w);                          \
        *(short4*)(&Xs[(xr     ) * XST + xc]) = h;                               \
        h.x = f2bf((buf).x1.x); h.y = f2bf((buf).x1.y);                          \
        h.z = f2bf((buf).x1.z); h.w = f2bf((buf).x1.w);                          \
        *(short4*)(&Xs[(xr + 16) * XST + xc]) = h;                               \
        h.x = f2bf((buf).x2.x); h.y = f2bf((buf).x2.y);                          \
        h.z = f2bf((buf).x2.z); h.w = f2bf((buf).x2.w);                          \
        *(short4*)(&Xs[(xr + 32) * XST + xc]) = h;                               \
        h.x = f2bf((buf).x3.x); h.y = f2bf((buf).x3.y);                          \
        h.z = f2bf((buf).x3.z); h.w = f2bf((buf).x3.w);                          \
        *(short4*)(&Xs[(xr + 48) * XST + xc]) = h;                               \
        h.x = f2bf((buf).p.x);  h.y = f2bf((buf).p.y);                           \
        h.z = f2bf((buf).p.z);  h.w = f2bf((buf).p.w);                           \
        *(short4*)(&Ps[xr * XST + xc]) = h;                                      \
    } while (0)

#define MFMA_BODY() do {                                                         \
        _Pragma("unroll")                                                        \
        for (int ks = 0; ks < 4; ++ks) {                                         \
            const int ko = ks * 32 + lg * 8;                                     \
            const bf16x8 fa  = *(const bf16x8*)(&Xs[(rt * 16 + lr) * XST + ko]); \
            const bf16x8 fb0 = *(const bf16x8*)(&Xs[((cp * 2    ) * 16 + lr) * XST + ko]); \
            const bf16x8 fb1 = *(const bf16x8*)(&Xs[((cp * 2 + 1) * 16 + lr) * XST + ko]); \
            accG0 = __builtin_amdgcn_mfma_f32_16x16x32_bf16(fa, fb0, accG0, 0, 0, 0); \
            accG1 = __builtin_amdgcn_mfma_f32_16x16x32_bf16(fa, fb1, accG1, 0, 0, 0); \
            if (cp == 0) {                                                       \
                const bf16x8 fp = *(const bf16x8*)(&Ps[lr * XST + ko]);          \
                accM = __builtin_amdgcn_mfma_f32_16x16x32_bf16(fa, fp, accM, 0, 0, 0); \
                if (wid == 0)                                                    \
                    accPP = __builtin_amdgcn_mfma_f32_16x16x32_bf16(fp, fp, accPP, 0, 0, 0); \
            }                                                                    \
        }                                                                        \
    } while (0)

    // ---------------- Phase 1: stream D in 8 chunks of 128, 4-deep prefetch
    Chunk c0, c1, c2, c3;
    LOADX(c0, 0); LOADX(c1, 1); LOADX(c2, 2); LOADX(c3, 3);  // issue early

    if (t < 64) lab_s[t] = labels[b * KK + t];
    for (int i = t; i < 16 * 72; i += 512) Ss[i] = 0;
    float bc = (lr < 8) ? b0[b * LL + lr] : 0.0f;   // bias replicated per lane

    f32x4 accG0 = {0,0,0,0}, accG1 = {0,0,0,0};
    f32x4 accM  = {0,0,0,0}, accPP = {0,0,0,0};

    for (int ch = 0; ch < NCH; ch += 4) {
        STOREC(c0); __syncthreads();
        if (ch + 4 < NCH) LOADX(c0, ch + 4);
        MFMA_BODY(); __syncthreads();

        STOREC(c1); __syncthreads();
        if (ch + 5 < NCH) LOADX(c1, ch + 5);
        MFMA_BODY(); __syncthreads();

        STOREC(c2); __syncthreads();
        if (ch + 6 < NCH) LOADX(c2, ch + 6);
        MFMA_BODY(); __syncthreads();

        STOREC(c3); __syncthreads();
        if (ch + 7 < NCH) LOADX(c3, ch + 7);
        MFMA_BODY(); __syncthreads();
    }

    // ---------------- Phase 2: spill G (bf16), M (f32), p0
    // C/D layout: row = (lg*4 + r), col = lr within each 16x16 tile
    #pragma unroll
    for (int r = 0; r < 4; ++r) {
        const int row = rt * 16 + lg * 4 + r;
        Gs[row * 72 + (cp * 2    ) * 16 + lr] = f2bf(accG0[r]);
        Gs[row * 72 + (cp * 2 + 1) * 16 + lr] = f2bf(accG1[r]);
    }
    if (cp == 0) {
        #pragma unroll
        for (int r = 0; r < 4; ++r)
            Ms[(rt * 16 + lg * 4 + r) * 16 + lr] = accM[r];
    }
    if (wid == 0 && lg == 2) p0_s[lr] = accPP[0];  // row 8 of P P^T = e . P[col]
    __syncthreads();

    // ---------------- Phase 3: 20-step SGD; waves 4-7 duplicate waves 0-3
    // (harmless; only waves 0-3 write shared state; all execute all barriers)
    const bf16x8 ga0 = *(const bf16x8*)(&Gs[(rt * 16 + lr) * 72 +  0 + lg * 8]);
    const bf16x8 ga1 = *(const bf16x8*)(&Gs[(rt * 16 + lr) * 72 + 32 + lg * 8]);

    const int row0 = rt * 16 + lg * 4;
    const float yv0 = (lab_s[row0 + 0] == lr) ? 1.0f : 0.0f;
    const float yv1 = (lab_s[row0 + 1] == lr) ? 1.0f : 0.0f;
    const float yv2 = (lab_s[row0 + 2] == lr) ? 1.0f : 0.0f;
    const float yv3 = (lab_s[row0 + 3] == lr) ? 1.0f : 0.0f;

    const float m00 = Ms[(row0 + 0) * 16 + lr];
    const float m01 = Ms[(row0 + 1) * 16 + lr];
    const float m02 = Ms[(row0 + 2) * 16 + lr];
    const float m03 = Ms[(row0 + 3) * 16 + lr];

    float s0 = 0.f, s1 = 0.f, s2 = 0.f, s3 = 0.f;
    float ct = 1.0f;

    for (int step = 0; step < NSTEPS; ++step) {
        const bf16x8 sb0 = *(const bf16x8*)(&Ss[lr * 72 +  0 + lg * 8]);
        const bf16x8 sb1 = *(const bf16x8*)(&Ss[lr * 72 + 32 + lg * 8]);
        f32x4 o = {0.f, 0.f, 0.f, 0.f};
        o = __builtin_amdgcn_mfma_f32_16x16x32_bf16(ga0, sb0, o, 0, 0, 0);
        o = __builtin_amdgcn_mfma_f32_16x16x32_bf16(ga1, sb1, o, 0, 0, 0);
        const float d0 = ct * m00 + o[0] + bc - yv0;
        const float d1 = ct * m01 + o[1] + bc - yv1;
        const float d2 = ct * m02 + o[2] + bc - yv2;
        const float d3 = ct * m03 + o[3] + bc - yv3;
        s0 = CD * s0 - LRS * d0;
        s1 = CD * s1 - LRS * d1;
        s2 = CD * s2 - LRS * d2;
        s3 = CD * s3 - LRS * d3;
        ct *= CD;
        // wave-local column sum over this wave's 16 rows (xor 16/32 keeps lr)
        float colp = d0 + d1 + d2 + d3;
        colp += __shfl_xor(colp, 16, 64);
        colp += __shfl_xor(colp, 32, 64);
        __syncthreads();                        // all waves done reading Ss
        if (wid < 4) {
            short4 sp;
            sp.x = f2bf(s0); sp.y = f2bf(s1); sp.z = f2bf(s2); sp.w = f2bf(s3);
            *(short4*)(&Ss[lr * 72 + row0]) = sp;   // S^T[col][k]
            if (lg == 0) red[wid * 16 + lr] = colp;
        }
        __syncthreads();
        bc = CD * bc - LRS * (red[0 * 16 + lr] + red[1 * 16 + lr] +
                              red[2 * 16 + lr] + red[3 * 16 + lr]);
    }

    // ---------------- Final: logits = c^20*p0 + q^T S + b   (q = Ms col 8)
    const float part = Ms[(row0 + 0) * 16 + 8] * s0 + Ms[(row0 + 1) * 16 + 8] * s1 +
                       Ms[(row0 + 2) * 16 + 8] * s2 + Ms[(row0 + 3) * 16 + 8] * s3;
    __syncthreads();                            // last bc read done; red reusable
    if (wid < 4) red[(wid * 4 + lg) * 16 + lr] = part;
    __syncthreads();
    if (t < 8) {
        float a = 0.f;
        #pragma unroll
        for (int i = 0; i < 16; ++i) a += red[i * 16 + t];
        out[b * LL + t] = ct * p0_s[t] + a + bc;  // thread t: lr==t -> bc=bias[t]
    }
}

extern "C" void kernel_launch(void* const* d_in, const int* in_sizes, int n_in,
                              void* d_out, int out_size, void* d_ws, size_t ws_size,
                              hipStream_t stream) {
    const float* demo   = (const float*)d_in[0]; // demo_embeddings [512,64,1024]
    const float* emb    = (const float*)d_in[1]; // embeddings     [512,1024]
    const float* W0     = (const float*)d_in[2]; // W0             [512,8,1024]
    const float* b0     = (const float*)d_in[3]; // b0             [512,8]
    const int*   labels = (const int*)d_in[4];   // demo_labels    [512,64]
    float* out = (float*)d_out;                  // logits         [512,8] f32
    (void)in_sizes; (void)n_in; (void)out_size; (void)d_ws; (void)ws_size;
    hipLaunchKernelGGL(knn_linear_fix_kernel, dim3(BB), dim3(512), 0, stream,
                       demo, emb, W0, b0, labels, out);
}

// Round 4
// 35.629 us; speedup vs baseline: 1.1601x; 1.1601x over previous
//
#include <hip/hip_runtime.h>

// KnnLinearFixModel: B=512, K=64, D=1024, L=8, 20 SGD steps.
// W_t = c^t*W0 + A_t*X (c=1-LR*WD) -> only G=X*X^T, M0=X*W0^T, q=X*e, p0=W0*e
// are needed; the 20-step loop runs on 64x8 state on-chip.
// R4: back to 256-thread blocks (R3's 512-thr collapsed prefetch: 64 VGPRs).
// Phase 1 rebuilt as T3/T4 pipeline: double-buffered LDS, ONE raw s_barrier
// per chunk with lgkmcnt(0) only -- global loads stay in flight across
// barriers (hipcc's __syncthreads drains vmcnt(0), which serialized R2).

#define BB 512
#define KK 64
#define DD 1024
#define LL 8
#define NSTEPS 20

typedef __attribute__((ext_vector_type(8))) short bf16x8;
typedef __attribute__((ext_vector_type(4))) float f32x4;

__device__ __forceinline__ short f2bf(float f) {
    // round-to-nearest-even f32 -> bf16 (finite inputs only)
    unsigned u = __float_as_uint(f);
    unsigned r = (u + 0x7FFFu + ((u >> 16) & 1u)) >> 16;
    return (short)r;
}

struct Chunk {
    float4 x0, x1, x2, x3;  // X rows xr, xr+16, xr+32, xr+48
    float4 p;               // P row xr (W0 rows 0-7, e at row 8, zeros 9-15)
};

// LDS-writes-visible barrier that does NOT drain global loads (T3/T4).
#define PIPE_SYNC() do {                                      \
        __builtin_amdgcn_sched_barrier(0);                    \
        asm volatile("s_waitcnt lgkmcnt(0)" ::: "memory");    \
        __builtin_amdgcn_s_barrier();                         \
        __builtin_amdgcn_sched_barrier(0);                    \
    } while (0)

__global__ __launch_bounds__(256, 2)
void knn_linear_fix_kernel(const float* __restrict__ demo,   // [B,K,D]
                           const float* __restrict__ emb,    // [B,D]
                           const float* __restrict__ W0,     // [B,L,D]
                           const float* __restrict__ b0,     // [B,L]
                           const int*   __restrict__ labels, // [B,K]
                           float* __restrict__ out)          // [B,L]
{
    const int b    = blockIdx.x;
    const int t    = threadIdx.x;
    const int lane = t & 63;
    const int wid  = t >> 6;          // wave id 0..3
    const int lg   = lane >> 4;       // lane group 0..3
    const int lr   = lane & 15;       // row (A) / col (B, C/D) index

    const float LR  = 1e-4f;
    const float WD  = 0.01f;
    const float LRS = LR * (2.0f / (float)(KK * LL)); // 3.90625e-7
    const float CD  = 1.0f - LR * WD;

    // stride 72 shorts (144 B rows) avoids the 128B-stride bank pathology
    __shared__ short Xs[2][64 * 72]; // X chunk double buffer, bf16 (18.4 KB)
    __shared__ short Ps[2][16 * 72]; // W0 rows 0-7, e row 8, zeros 9-15 (4.6 KB)
    __shared__ short Gs[64 * 72];    // G = X X^T, bf16
    __shared__ short Ss[16 * 72];    // S^T: [col][k-row], bf16
    __shared__ float red[256];       // cross-wave reduction buffer
    __shared__ float p0_s[16];       // p0 = W0 . e
    __shared__ float q_s[64];        // q  = X . e
    __shared__ int   lab_s[64];

    const float* Xg = demo + (size_t)b * (KK * DD);
    const float* Wg = W0   + (size_t)b * (LL * DD);
    const float* eg = emb  + (size_t)b * DD;

    const int xr = t >> 4;          // staging row 0..15
    const int xc = (t & 15) * 4;    // staging col (floats)

#define LOADX(buf, CH) do {                                                      \
        const int dk = (CH) * 64;                                                \
        (buf).x0 = *(const float4*)(Xg + (size_t)(xr     ) * DD + dk + xc);      \
        (buf).x1 = *(const float4*)(Xg + (size_t)(xr + 16) * DD + dk + xc);      \
        (buf).x2 = *(const float4*)(Xg + (size_t)(xr + 32) * DD + dk + xc);      \
        (buf).x3 = *(const float4*)(Xg + (size_t)(xr + 48) * DD + dk + xc);      \
        if (xr < 8)       (buf).p = *(const float4*)(Wg + (size_t)xr * DD + dk + xc); \
        else if (xr == 8) (buf).p = *(const float4*)(eg + dk + xc);              \
        else              (buf).p = make_float4(0.f, 0.f, 0.f, 0.f);             \
    } while (0)

#define STOREC(buf, BI) do {                                                     \
        short4 h;                                                                \
        h.x = f2bf((buf).x0.x); h.y = f2bf((buf).x0.y);                          \
        h.z = f2bf((buf).x0.z); h.w = f2bf((buf).x0.w);                          \
        *(short4*)(&Xs[BI][(xr     ) * 72 + xc]) = h;                            \
        h.x = f2bf((buf).x1.x); h.y = f2bf((buf).x1.y);                          \
        h.z = f2bf((buf).x1.z); h.w = f2bf((buf).x1.w);                          \
        *(short4*)(&Xs[BI][(xr + 16) * 72 + xc]) = h;                            \
        h.x = f2bf((buf).x2.x); h.y = f2bf((buf).x2.y);                          \
        h.z = f2bf((buf).x2.z); h.w = f2bf((buf).x2.w);                          \
        *(short4*)(&Xs[BI][(xr + 32) * 72 + xc]) = h;                            \
        h.x = f2bf((buf).x3.x); h.y = f2bf((buf).x3.y);                          \
        h.z = f2bf((buf).x3.z); h.w = f2bf((buf).x3.w);                          \
        *(short4*)(&Xs[BI][(xr + 48) * 72 + xc]) = h;                            \
        h.x = f2bf((buf).p.x);  h.y = f2bf((buf).p.y);                           \
        h.z = f2bf((buf).p.z);  h.w = f2bf((buf).p.w);                           \
        *(short4*)(&Ps[BI][xr * 72 + xc]) = h;                                   \
    } while (0)

#define MFMA_BODY(BI) do {                                                       \
        _Pragma("unroll")                                                        \
        for (int ks = 0; ks < 2; ++ks) {                                         \
            const int ko = ks * 32 + lg * 8;                                     \
            const bf16x8 fa = *(const bf16x8*)(&Xs[BI][(wid * 16 + lr) * 72 + ko]); \
            const bf16x8 f0 = *(const bf16x8*)(&Xs[BI][( 0 + lr) * 72 + ko]);    \
            const bf16x8 f1 = *(const bf16x8*)(&Xs[BI][(16 + lr) * 72 + ko]);    \
            const bf16x8 f2 = *(const bf16x8*)(&Xs[BI][(32 + lr) * 72 + ko]);    \
            const bf16x8 f3 = *(const bf16x8*)(&Xs[BI][(48 + lr) * 72 + ko]);    \
            const bf16x8 fp = *(const bf16x8*)(&Ps[BI][lr * 72 + ko]);           \
            accG0 = __builtin_amdgcn_mfma_f32_16x16x32_bf16(fa, f0, accG0, 0, 0, 0); \
            accG1 = __builtin_amdgcn_mfma_f32_16x16x32_bf16(fa, f1, accG1, 0, 0, 0); \
            accG2 = __builtin_amdgcn_mfma_f32_16x16x32_bf16(fa, f2, accG2, 0, 0, 0); \
            accG3 = __builtin_amdgcn_mfma_f32_16x16x32_bf16(fa, f3, accG3, 0, 0, 0); \
            accM  = __builtin_amdgcn_mfma_f32_16x16x32_bf16(fa, fp, accM , 0, 0, 0); \
            accPP = __builtin_amdgcn_mfma_f32_16x16x32_bf16(fp, fp, accPP, 0, 0, 0); \
        }                                                                        \
    } while (0)

    // ---------------- Phase 1: 16 chunks of 64 cols; dbuf + 1 raw barrier/chunk
    Chunk c0, c1, c2, c3;
    LOADX(c0, 0); LOADX(c1, 1); LOADX(c2, 2); LOADX(c3, 3);   // issue early

    if (t < 64) lab_s[t] = labels[b * KK + t];
    for (int i = t; i < 16 * 72; i += 256) Ss[i] = 0;
    float bc = (lr < 8) ? b0[b * LL + lr] : 0.0f;   // bias replicated per lane

    f32x4 accG0 = {0,0,0,0}, accG1 = {0,0,0,0}, accG2 = {0,0,0,0}, accG3 = {0,0,0,0};
    f32x4 accM  = {0,0,0,0}, accPP = {0,0,0,0};

    STOREC(c0, 0);            // chunk 0 -> buf 0
    PIPE_SYNC();
    LOADX(c0, 4);             // chunk 4 in flight

    // iter i: MFMA(chunk i, buf i&1); store chunk i+1 -> buf (i+1)&1;
    // issue load of chunk i+5; barrier. The single barrier covers both
    // write-visible (i+1) and read-done (buf (i+1)&1 last read at iter i-1).
    for (int ch = 0; ch < 16; ch += 4) {
        MFMA_BODY(0);
        STOREC(c1, 1); if (ch + 5 < 16) LOADX(c1, ch + 5);
        PIPE_SYNC();

        MFMA_BODY(1);
        STOREC(c2, 0); if (ch + 6 < 16) LOADX(c2, ch + 6);
        PIPE_SYNC();

        MFMA_BODY(0);
        STOREC(c3, 1); if (ch + 7 < 16) LOADX(c3, ch + 7);
        PIPE_SYNC();

        MFMA_BODY(1);
        if (ch + 4 < 16) {
            STOREC(c0, 0); if (ch + 8 < 16) LOADX(c0, ch + 8);
        }
        PIPE_SYNC();
    }

    // ---------------- Phase 2: spill G (bf16), q, p0; C/D: row=(lg*4+r), col=lr
    #pragma unroll
    for (int r = 0; r < 4; ++r) {
        const int row = wid * 16 + lg * 4 + r;
        Gs[row * 72 +  0 + lr] = f2bf(accG0[r]);
        Gs[row * 72 + 16 + lr] = f2bf(accG1[r]);
        Gs[row * 72 + 32 + lr] = f2bf(accG2[r]);
        Gs[row * 72 + 48 + lr] = f2bf(accG3[r]);
    }
    if (lr == 8) {
        #pragma unroll
        for (int r = 0; r < 4; ++r) q_s[wid * 16 + lg * 4 + r] = accM[r];
    }
    if (wid == 0 && lg == 2) p0_s[lr] = accPP[0];  // row 8 of P P^T = e . P[col]
    __syncthreads();

    // ---------------- Phase 3: 20-step SGD on 64x8 state
    const bf16x8 ga0 = *(const bf16x8*)(&Gs[(wid * 16 + lr) * 72 +  0 + lg * 8]);
    const bf16x8 ga1 = *(const bf16x8*)(&Gs[(wid * 16 + lr) * 72 + 32 + lg * 8]);

    const int row0 = wid * 16 + lg * 4;
    const float yv0 = (lab_s[row0 + 0] == lr) ? 1.0f : 0.0f;
    const float yv1 = (lab_s[row0 + 1] == lr) ? 1.0f : 0.0f;
    const float yv2 = (lab_s[row0 + 2] == lr) ? 1.0f : 0.0f;
    const float yv3 = (lab_s[row0 + 3] == lr) ? 1.0f : 0.0f;

    const float m00 = accM[0], m01 = accM[1], m02 = accM[2], m03 = accM[3];
    float s0 = 0.f, s1 = 0.f, s2 = 0.f, s3 = 0.f;
    float ct = 1.0f;

    for (int step = 0; step < NSTEPS; ++step) {
        const bf16x8 sb0 = *(const bf16x8*)(&Ss[lr * 72 +  0 + lg * 8]);
        const bf16x8 sb1 = *(const bf16x8*)(&Ss[lr * 72 + 32 + lg * 8]);
        f32x4 o = {0.f, 0.f, 0.f, 0.f};
        o = __builtin_amdgcn_mfma_f32_16x16x32_bf16(ga0, sb0, o, 0, 0, 0);
        o = __builtin_amdgcn_mfma_f32_16x16x32_bf16(ga1, sb1, o, 0, 0, 0);
        const float d0 = ct * m00 + o[0] + bc - yv0;
        const float d1 = ct * m01 + o[1] + bc - yv1;
        const float d2 = ct * m02 + o[2] + bc - yv2;
        const float d3 = ct * m03 + o[3] + bc - yv3;
        s0 = CD * s0 - LRS * d0;
        s1 = CD * s1 - LRS * d1;
        s2 = CD * s2 - LRS * d2;
        s3 = CD * s3 - LRS * d3;
        ct *= CD;
        // wave-local column sum over this wave's 16 rows (xor 16/32 keeps lr)
        float colp = d0 + d1 + d2 + d3;
        colp += __shfl_xor(colp, 16, 64);
        colp += __shfl_xor(colp, 32, 64);
        __syncthreads();                        // all waves done reading Ss
        short4 sp;
        sp.x = f2bf(s0); sp.y = f2bf(s1); sp.z = f2bf(s2); sp.w = f2bf(s3);
        *(short4*)(&Ss[lr * 72 + row0]) = sp;   // S^T[col][k]
        if (lg == 0) red[wid * 16 + lr] = colp;
        __syncthreads();
        bc = CD * bc - LRS * (red[0 * 16 + lr] + red[1 * 16 + lr] +
                              red[2 * 16 + lr] + red[3 * 16 + lr]);
    }

    // ---------------- Final: logits = c^20*p0 + q^T S + b
    const float part = q_s[row0 + 0] * s0 + q_s[row0 + 1] * s1 +
                       q_s[row0 + 2] * s2 + q_s[row0 + 3] * s3;
    __syncthreads();                            // last bc read done; red reusable
    red[(wid * 4 + lg) * 16 + lr] = part;
    __syncthreads();
    if (t < 8) {
        float a = 0.f;
        #pragma unroll
        for (int i = 0; i < 16; ++i) a += red[i * 16 + t];
        out[b * LL + t] = ct * p0_s[t] + a + bc;  // thread t: lr==t -> bc=bias[t]
    }
}

extern "C" void kernel_launch(void* const* d_in, const int* in_sizes, int n_in,
                              void* d_out, int out_size, void* d_ws, size_t ws_size,
                              hipStream_t stream) {
    const float* demo   = (const float*)d_in[0]; // demo_embeddings [512,64,1024]
    const float* emb    = (const float*)d_in[1]; // embeddings     [512,1024]
    const float* W0     = (const float*)d_in[2]; // W0             [512,8,1024]
    const float* b0     = (const float*)d_in[3]; // b0             [512,8]
    const int*   labels = (const int*)d_in[4];   // demo_labels    [512,64]
    float* out = (float*)d_out;                  // logits         [512,8] f32
    (void)in_sizes; (void)n_in; (void)out_size; (void)d_ws; (void)ws_size;
    hipLaunchKernelGGL(knn_linear_fix_kernel, dim3(BB), dim3(256), 0, stream,
                       demo, emb, W0, b0, labels, out);
}

// Round 5
// 34.946 us; speedup vs baseline: 1.1827x; 1.0195x over previous
//
#include <hip/hip_runtime.h>

// KnnLinearFixModel: B=512, K=64, D=1024, L=8, 20 SGD steps.
// W_t = c^t*W0 + A_t*X (c=1-LR*WD) -> only G=X*X^T, M0=X*W0^T, q=X*e, p0=W0*e
// needed; the 20-step loop runs on 64x8 state on-chip.
// R5: barrier-free phase 1. One wave owns one D-slice (256 cols); Gram trick
// means 5 frag reads feed 15 MFMAs (10 upper-tri G + 4 M + 1 PP) -> LDS reads
// per chunk drop 5x vs R4, zero barriers (wave-private staging, in-order LDS
// pipe). f32 partial reduce across waves at the end; G mirrored by symmetry
// (bitwise-safe: mfma(fi,fj)[r][c] and mfma(fj,fi)[c][r] sum identical
// products in identical k-order).

#define BB 512
#define KK 64
#define DD 1024
#define LL 8
#define NSTEPS 20

#define SROWS 80             // 64 X rows + 16 P rows (0-7 W0, 8 e, 9-15 zero)
#define SSTR  72             // shorts/row: 144 B, 16B-aligned rows for b128
#define NTILE 15             // 10 G (upper tri) + 4 M + 1 PP
#define ARENA_BYTES (4 * NTILE * 256 * 4)   // 61440; staging needs 4*11520

typedef __attribute__((ext_vector_type(8))) short bf16x8;
typedef __attribute__((ext_vector_type(4))) float f32x4;

__device__ __forceinline__ short f2bf(float f) {
    // round-to-nearest-even f32 -> bf16 (finite inputs only)
    unsigned u = __float_as_uint(f);
    unsigned r = (u + 0x7FFFu + ((u >> 16) & 1u)) >> 16;
    return (short)r;
}

#define MFMA16(A, B, C) __builtin_amdgcn_mfma_f32_16x16x32_bf16(A, B, C, 0, 0, 0)

__global__ __launch_bounds__(256, 2)
void knn_linear_fix_kernel(const float* __restrict__ demo,   // [B,K,D]
                           const float* __restrict__ emb,    // [B,D]
                           const float* __restrict__ W0,     // [B,L,D]
                           const float* __restrict__ b0,     // [B,L]
                           const int*   __restrict__ labels, // [B,K]
                           float* __restrict__ out)          // [B,L]
{
    const int b    = blockIdx.x;
    const int t    = threadIdx.x;
    const int lane = t & 63;
    const int wid  = t >> 6;          // wave id 0..3 == D-slice id
    const int lg   = lane >> 4;       // lane group 0..3
    const int lr   = lane & 15;       // row (A) / col (B, C/D) index

    const float LR  = 1e-4f;
    const float WD  = 0.01f;
    const float LRS = LR * (2.0f / (float)(KK * LL)); // 3.90625e-7
    const float CD  = 1.0f - LR * WD;

    __shared__ __align__(16) char arena[ARENA_BYTES]; // staging / exchange
    __shared__ short Gs[64 * 72];    // G bf16, stride 72
    __shared__ short Ss[16 * 72];    // S^T: [col][k-row], bf16
    __shared__ float Ms[64 * 16];    // cols 0-7 = M0 = X W0^T, col 8 = q = X.e
    __shared__ float red[256];
    __shared__ float p0_s[16];       // p0 = W0 . e
    __shared__ int   lab_s[64];

    const float* Xg = demo + (size_t)b * (KK * DD);
    const float* Wg = W0   + (size_t)b * (LL * DD);
    const float* eg = emb  + (size_t)b * DD;

    short* Xw = (short*)arena + wid * (SROWS * SSTR);  // wave-private staging
    float* Ex = (float*)arena;                         // exchange view

    // small early loads + persistent init
    if (t < 64) lab_s[t] = labels[b * KK + t];
    float bc = (lr < 8) ? b0[b * LL + lr] : 0.0f;      // bias, replicated
    for (int i = t; i < 16 * 72; i += 256) Ss[i] = 0;

    // zero wave-private staging pad rows 73..79 (P rows 9-15), once
    {
        int* zp = (int*)(Xw + 73 * SSTR);
        for (int i = lane; i < (7 * SSTR) / 2; i += 64) zp[i] = 0;
    }

    const int g  = lane >> 4;        // load row-group 0..3
    const int cl = (lane & 15) * 4;  // load col (floats): 16 lanes x 16B = 256B

    float4 xb[16]; float4 pb[3];

#define LOADCH(CH) do {                                                          \
        const int doff = wid * 256 + (CH) * 64;                                  \
        _Pragma("unroll")                                                        \
        for (int r = 0; r < 16; ++r)                                             \
            xb[r] = *(const float4*)(Xg + (size_t)(r * 4 + g) * DD + doff + cl); \
        pb[0] = *(const float4*)(Wg + (size_t)(g    ) * DD + doff + cl);         \
        pb[1] = *(const float4*)(Wg + (size_t)(g + 4) * DD + doff + cl);         \
        pb[2] = (g == 0) ? *(const float4*)(eg + doff + cl)                      \
                         : make_float4(0.f, 0.f, 0.f, 0.f);                      \
    } while (0)

#define ST1(ROW, V) do {                                                         \
        short4 h;                                                                \
        h.x = f2bf((V).x); h.y = f2bf((V).y);                                    \
        h.z = f2bf((V).z); h.w = f2bf((V).w);                                    \
        *(short4*)(&Xw[(ROW) * SSTR + cl]) = h;                                  \
    } while (0)

#define STORECH() do {                                                           \
        _Pragma("unroll")                                                        \
        for (int r = 0; r < 16; ++r) ST1(r * 4 + g, xb[r]);                      \
        ST1(64 + g, pb[0]);                                                      \
        ST1(68 + g, pb[1]);                                                      \
        if (g == 0) ST1(72, pb[2]);                                              \
    } while (0)

#define FRAG(I, KS) (*(const bf16x8*)(&Xw[(16 * (I) + lr) * SSTR + lg * 8 + (KS) * 32]))
#define FRAGP(KS)   (*(const bf16x8*)(&Xw[(64 + lr) * SSTR + lg * 8 + (KS) * 32]))

    f32x4 g00 = {0,0,0,0}, g01 = {0,0,0,0}, g02 = {0,0,0,0}, g03 = {0,0,0,0};
    f32x4 g11 = {0,0,0,0}, g12 = {0,0,0,0}, g13 = {0,0,0,0};
    f32x4 g22 = {0,0,0,0}, g23 = {0,0,0,0}, g33 = {0,0,0,0};
    f32x4 am0 = {0,0,0,0}, am1 = {0,0,0,0}, am2 = {0,0,0,0}, am3 = {0,0,0,0};
    f32x4 app = {0,0,0,0};

    // ---------------- Phase 1: 4 chunks of 64 cols per wave, no barriers
    LOADCH(0);
    for (int ch = 0; ch < 4; ++ch) {
        STORECH();                       // waits its loads; in-order LDS pipe
        if (ch < 3) LOADCH(ch + 1);      // next chunk in flight during MFMAs
        __builtin_amdgcn_sched_barrier(0);
        #pragma unroll
        for (int ks = 0; ks < 2; ++ks) {
            const bf16x8 f0 = FRAG(0, ks), f1 = FRAG(1, ks);
            const bf16x8 f2 = FRAG(2, ks), f3 = FRAG(3, ks);
            const bf16x8 fp = FRAGP(ks);
            g00 = MFMA16(f0, f0, g00); g01 = MFMA16(f0, f1, g01);
            g02 = MFMA16(f0, f2, g02); g03 = MFMA16(f0, f3, g03);
            g11 = MFMA16(f1, f1, g11); g12 = MFMA16(f1, f2, g12);
            g13 = MFMA16(f1, f3, g13);
            g22 = MFMA16(f2, f2, g22); g23 = MFMA16(f2, f3, g23);
            g33 = MFMA16(f3, f3, g33);
            am0 = MFMA16(f0, fp, am0); am1 = MFMA16(f1, fp, am1);
            am2 = MFMA16(f2, fp, am2); am3 = MFMA16(f3, fp, am3);
            app = MFMA16(fp, fp, app);
        }
        __builtin_amdgcn_sched_barrier(0);
    }

    // ---------------- Phase 2: cross-wave f32 reduce of 15 tiles, scatter
    __syncthreads();                    // staging regions -> exchange arena
    {
        float* Exw = Ex + wid * (NTILE * 256);
        const int ro = (lg * 4) * 16 + lr;   // C/D: row=lg*4+r, col=lr
#define PUT(IDX, ACC) { _Pragma("unroll") \
        for (int r = 0; r < 4; ++r) Exw[(IDX) * 256 + ro + r * 16] = (ACC)[r]; }
        PUT(0, g00) PUT(1, g01) PUT(2, g02) PUT(3, g03)
        PUT(4, g11) PUT(5, g12) PUT(6, g13)
        PUT(7, g22) PUT(8, g23) PUT(9, g33)
        PUT(10, am0) PUT(11, am1) PUT(12, am2) PUT(13, am3)
        PUT(14, app)
#undef PUT
    }
    __syncthreads();
    {
        const int er = t >> 4, ec = t & 15;      // entry (row, col) in a tile
        const int ti[10] = {0,0,0,0,1,1,1,2,2,3};
        const int tj[10] = {0,1,2,3,1,2,3,2,3,3};
        #pragma unroll
        for (int k = 0; k < 10; ++k) {
            float v = Ex[0 * NTILE * 256 + k * 256 + t]
                    + Ex[1 * NTILE * 256 + k * 256 + t]
                    + Ex[2 * NTILE * 256 + k * 256 + t]
                    + Ex[3 * NTILE * 256 + k * 256 + t];
            const short gv = f2bf(v);
            const int gr = ti[k] * 16 + er, gc = tj[k] * 16 + ec;
            Gs[gr * 72 + gc] = gv;
            Gs[gc * 72 + gr] = gv;      // symmetry (bitwise-equal on diagonal)
        }
        #pragma unroll
        for (int k = 0; k < 4; ++k) {
            float v = Ex[0 * NTILE * 256 + (10 + k) * 256 + t]
                    + Ex[1 * NTILE * 256 + (10 + k) * 256 + t]
                    + Ex[2 * NTILE * 256 + (10 + k) * 256 + t]
                    + Ex[3 * NTILE * 256 + (10 + k) * 256 + t];
            Ms[(k * 16 + er) * 16 + ec] = v;
        }
        {
            float v = Ex[0 * NTILE * 256 + 14 * 256 + t]
                    + Ex[1 * NTILE * 256 + 14 * 256 + t]
                    + Ex[2 * NTILE * 256 + 14 * 256 + t]
                    + Ex[3 * NTILE * 256 + 14 * 256 + t];
            if (er == 8) p0_s[ec] = v;  // row 8 of P P^T = e . P[col]
        }
    }
    __syncthreads();

    // ---------------- Phase 3: 20-step SGD on 64x8 state (4 waves)
    const bf16x8 ga0 = *(const bf16x8*)(&Gs[(wid * 16 + lr) * 72 +  0 + lg * 8]);
    const bf16x8 ga1 = *(const bf16x8*)(&Gs[(wid * 16 + lr) * 72 + 32 + lg * 8]);

    const int row0 = wid * 16 + lg * 4;
    const float yv0 = (lab_s[row0 + 0] == lr) ? 1.0f : 0.0f;
    const float yv1 = (lab_s[row0 + 1] == lr) ? 1.0f : 0.0f;
    const float yv2 = (lab_s[row0 + 2] == lr) ? 1.0f : 0.0f;
    const float yv3 = (lab_s[row0 + 3] == lr) ? 1.0f : 0.0f;

    const float m00 = Ms[(row0 + 0) * 16 + lr];
    const float m01 = Ms[(row0 + 1) * 16 + lr];
    const float m02 = Ms[(row0 + 2) * 16 + lr];
    const float m03 = Ms[(row0 + 3) * 16 + lr];

    float s0 = 0.f, s1 = 0.f, s2 = 0.f, s3 = 0.f;
    float ct = 1.0f;

    for (int step = 0; step < NSTEPS; ++step) {
        const bf16x8 sb0 = *(const bf16x8*)(&Ss[lr * 72 +  0 + lg * 8]);
        const bf16x8 sb1 = *(const bf16x8*)(&Ss[lr * 72 + 32 + lg * 8]);
        f32x4 o = {0.f, 0.f, 0.f, 0.f};
        o = MFMA16(ga0, sb0, o);
        o = MFMA16(ga1, sb1, o);
        const float d0 = ct * m00 + o[0] + bc - yv0;
        const float d1 = ct * m01 + o[1] + bc - yv1;
        const float d2 = ct * m02 + o[2] + bc - yv2;
        const float d3 = ct * m03 + o[3] + bc - yv3;
        s0 = CD * s0 - LRS * d0;
        s1 = CD * s1 - LRS * d1;
        s2 = CD * s2 - LRS * d2;
        s3 = CD * s3 - LRS * d3;
        ct *= CD;
        float colp = d0 + d1 + d2 + d3;          // wave-local column sum
        colp += __shfl_xor(colp, 16, 64);        // xor 16/32 keeps lr
        colp += __shfl_xor(colp, 32, 64);
        __syncthreads();                          // all waves done reading Ss
        short4 sp;
        sp.x = f2bf(s0); sp.y = f2bf(s1); sp.z = f2bf(s2); sp.w = f2bf(s3);
        *(short4*)(&Ss[lr * 72 + row0]) = sp;     // S^T[col][k]
        if (lg == 0) red[wid * 16 + lr] = colp;
        __syncthreads();
        bc = CD * bc - LRS * (red[0 * 16 + lr] + red[1 * 16 + lr] +
                              red[2 * 16 + lr] + red[3 * 16 + lr]);
    }

    // ---------------- Final: logits = c^20*p0 + q^T S + b   (q = Ms col 8)
    const float part = Ms[(row0 + 0) * 16 + 8] * s0 + Ms[(row0 + 1) * 16 + 8] * s1 +
                       Ms[(row0 + 2) * 16 + 8] * s2 + Ms[(row0 + 3) * 16 + 8] * s3;
    __syncthreads();
    red[(wid * 4 + lg) * 16 + lr] = part;
    __syncthreads();
    if (t < 8) {
        float a = 0.f;
        #pragma unroll
        for (int i = 0; i < 16; ++i) a += red[i * 16 + t];
        out[b * LL + t] = ct * p0_s[t] + a + bc;  // thread t: lr==t -> bc=bias[t]
    }
}

extern "C" void kernel_launch(void* const* d_in, const int* in_sizes, int n_in,
                              void* d_out, int out_size, void* d_ws, size_t ws_size,
                              hipStream_t stream) {
    const float* demo   = (const float*)d_in[0]; // demo_embeddings [512,64,1024]
    const float* emb    = (const float*)d_in[1]; // embeddings     [512,1024]
    const float* W0     = (const float*)d_in[2]; // W0             [512,8,1024]
    const float* b0     = (const float*)d_in[3]; // b0             [512,8]
    const int*   labels = (const int*)d_in[4];   // demo_labels    [512,64]
    float* out = (float*)d_out;                  // logits         [512,8] f32
    (void)in_sizes; (void)n_in; (void)out_size; (void)d_ws; (void)ws_size;
    hipLaunchKernelGGL(knn_linear_fix_kernel, dim3(BB), dim3(256), 0, stream,
                       demo, emb, W0, b0, labels, out);
}

// Round 6
// 29.985 us; speedup vs baseline: 1.3784x; 1.1654x over previous
//
#include <hip/hip_runtime.h>

// KnnLinearFixModel: B=512, K=64, D=1024, L=8, 20 SGD steps.
// W_t = c^t*W0 + S_t^T X (c=1-LR*WD) -> phase 1 computes G=X*X^T, M0=X*W0^T,
// q=X*e, p0=W0*e in one pass (MFMA Gram trick, validated R5).
// R6: phase 3 CLOSED FORM. The SGD recurrence is linear: z_{t+1}=F z_t+g_t,
// F = cI - LRS*H, H=[[G,1],[1^T G,64]]. logits = c^20 p0 + w^T z_20, w=[q;1].
// Binomial expansion in H (||LRS*H|| ~ 6.6e-4; m=3 term ~1e-10 rel) needs only
// w1=H^T w, w2=H^T w1 (two G-matvecs) + constexpr scalar coefficient sums.
// 20-step loop (40 barriers, ~6us tail) -> 2 MFMA matvecs + butterfly (~1us).

#define BB 512
#define KK 64
#define DD 1024
#define LL 8

#define SROWS 80             // 64 X rows + 16 P rows (0-7 W0, 8 e, 9-15 zero)
#define SSTR  72             // shorts/row: 144 B, 16B-aligned rows for b128
#define NTILE 15             // 10 G (upper tri) + 4 M + 1 PP
#define ARENA_BYTES (4 * NTILE * 256 * 4)   // 61440; staging needs 4*11520

typedef __attribute__((ext_vector_type(8))) short bf16x8;
typedef __attribute__((ext_vector_type(4))) float f32x4;

// ---- compile-time coefficient algebra (double, exact enough) ----
constexpr double dLRS = 1e-4 * 2.0 / (64.0 * 8.0);   // LR*scale = 3.90625e-7
constexpr double dC   = 1.0 - 1e-4 * 0.01;           // c = 1 - LR*WD
constexpr double dpow(double x, int n) { double r = 1; for (int i = 0; i < n; ++i) r *= x; return r; }
// P1 = sum_{t=0..19} c^t F^{19-t} = sum_m C(20,m+1) c^{19-m} (-LRS H)^m
// P2 = sum_{j=0..19} F^j        = sum_m D_m (-LRS H)^m, D_m = sum_j C(j,m)c^{j-m}
// F^20 = sum_m C(20,m) c^{20-m} (-LRS H)^m
constexpr double dD0() { double s = 0; for (int j = 0; j < 20; ++j) s += dpow(dC, j); return s; }
constexpr double dD1() { double s = 0; for (int j = 1; j < 20; ++j) s += j * dpow(dC, j - 1); return s; }
constexpr double dD2() { double s = 0; for (int j = 2; j < 20; ++j) s += (j * (j - 1) / 2) * dpow(dC, j - 2); return s; }

__device__ __forceinline__ short f2bf(float f) {
    // round-to-nearest-even f32 -> bf16 (finite inputs only)
    unsigned u = __float_as_uint(f);
    unsigned r = (u + 0x7FFFu + ((u >> 16) & 1u)) >> 16;
    return (short)r;
}

#define MFMA16(A, B, C) __builtin_amdgcn_mfma_f32_16x16x32_bf16(A, B, C, 0, 0, 0)

__global__ __launch_bounds__(256, 2)
void knn_linear_fix_kernel(const float* __restrict__ demo,   // [B,K,D]
                           const float* __restrict__ emb,    // [B,D]
                           const float* __restrict__ W0,     // [B,L,D]
                           const float* __restrict__ b0,     // [B,L]
                           const int*   __restrict__ labels, // [B,K]
                           float* __restrict__ out)          // [B,L]
{
    const int b    = blockIdx.x;
    const int t    = threadIdx.x;
    const int lane = t & 63;
    const int wid  = t >> 6;          // wave id 0..3 == D-slice id
    const int lg   = lane >> 4;       // lane group 0..3
    const int lr   = lane & 15;       // row (A) / col (B, C/D) index

    __shared__ __align__(16) char arena[ARENA_BYTES]; // staging / exchange
    __shared__ short Gs[64 * 72];    // G bf16, stride 72
    __shared__ short Ss[16 * 72];    // broadcast t-vector as B-frag [col][k]
    __shared__ float Ms[64 * 16];    // cols 0-7 = M0 = X W0^T, col 8 = q = X.e
    __shared__ float red[256];
    __shared__ float p0_s[16];       // p0 = W0 . e
    __shared__ int   lab_s[64];

    const float* Xg = demo + (size_t)b * (KK * DD);
    const float* Wg = W0   + (size_t)b * (LL * DD);
    const float* eg = emb  + (size_t)b * DD;

    short* Xw = (short*)arena + wid * (SROWS * SSTR);  // wave-private staging
    float* Ex = (float*)arena;                         // exchange view

    if (t < 64) lab_s[t] = labels[b * KK + t];
    float bc = (lr < 8) ? b0[b * LL + lr] : 0.0f;      // bias, replicated

    // zero wave-private staging pad rows 73..79 (P rows 9-15), once
    {
        int* zp = (int*)(Xw + 73 * SSTR);
        for (int i = lane; i < (7 * SSTR) / 2; i += 64) zp[i] = 0;
    }

    const int g  = lane >> 4;        // load row-group 0..3
    const int cl = (lane & 15) * 4;  // load col (floats): 16 lanes x 16B = 256B

    float4 xb[16]; float4 pb[3];

#define LOADCH(CH) do {                                                          \
        const int doff = wid * 256 + (CH) * 64;                                  \
        _Pragma("unroll")                                                        \
        for (int r = 0; r < 16; ++r)                                             \
            xb[r] = *(const float4*)(Xg + (size_t)(r * 4 + g) * DD + doff + cl); \
        pb[0] = *(const float4*)(Wg + (size_t)(g    ) * DD + doff + cl);         \
        pb[1] = *(const float4*)(Wg + (size_t)(g + 4) * DD + doff + cl);         \
        pb[2] = (g == 0) ? *(const float4*)(eg + doff + cl)                      \
                         : make_float4(0.f, 0.f, 0.f, 0.f);                      \
    } while (0)

#define ST1(ROW, V) do {                                                         \
        short4 h;                                                                \
        h.x = f2bf((V).x); h.y = f2bf((V).y);                                    \
        h.z = f2bf((V).z); h.w = f2bf((V).w);                                    \
        *(short4*)(&Xw[(ROW) * SSTR + cl]) = h;                                  \
    } while (0)

#define STORECH() do {                                                           \
        _Pragma("unroll")                                                        \
        for (int r = 0; r < 16; ++r) ST1(r * 4 + g, xb[r]);                      \
        ST1(64 + g, pb[0]);                                                      \
        ST1(68 + g, pb[1]);                                                      \
        if (g == 0) ST1(72, pb[2]);                                              \
    } while (0)

#define FRAG(I, KS) (*(const bf16x8*)(&Xw[(16 * (I) + lr) * SSTR + lg * 8 + (KS) * 32]))
#define FRAGP(KS)   (*(const bf16x8*)(&Xw[(64 + lr) * SSTR + lg * 8 + (KS) * 32]))

    f32x4 g00 = {0,0,0,0}, g01 = {0,0,0,0}, g02 = {0,0,0,0}, g03 = {0,0,0,0};
    f32x4 g11 = {0,0,0,0}, g12 = {0,0,0,0}, g13 = {0,0,0,0};
    f32x4 g22 = {0,0,0,0}, g23 = {0,0,0,0}, g33 = {0,0,0,0};
    f32x4 am0 = {0,0,0,0}, am1 = {0,0,0,0}, am2 = {0,0,0,0}, am3 = {0,0,0,0};
    f32x4 app = {0,0,0,0};

    // ---------------- Phase 1: 4 chunks of 64 cols per wave, no barriers
    LOADCH(0);
    for (int ch = 0; ch < 4; ++ch) {
        STORECH();                       // waits its loads; in-order LDS pipe
        if (ch < 3) LOADCH(ch + 1);      // next chunk in flight during MFMAs
        __builtin_amdgcn_sched_barrier(0);
        #pragma unroll
        for (int ks = 0; ks < 2; ++ks) {
            const bf16x8 f0 = FRAG(0, ks), f1 = FRAG(1, ks);
            const bf16x8 f2 = FRAG(2, ks), f3 = FRAG(3, ks);
            const bf16x8 fp = FRAGP(ks);
            g00 = MFMA16(f0, f0, g00); g01 = MFMA16(f0, f1, g01);
            g02 = MFMA16(f0, f2, g02); g03 = MFMA16(f0, f3, g03);
            g11 = MFMA16(f1, f1, g11); g12 = MFMA16(f1, f2, g12);
            g13 = MFMA16(f1, f3, g13);
            g22 = MFMA16(f2, f2, g22); g23 = MFMA16(f2, f3, g23);
            g33 = MFMA16(f3, f3, g33);
            am0 = MFMA16(f0, fp, am0); am1 = MFMA16(f1, fp, am1);
            am2 = MFMA16(f2, fp, am2); am3 = MFMA16(f3, fp, am3);
            app = MFMA16(fp, fp, app);
        }
        __builtin_amdgcn_sched_barrier(0);
    }

    // ---------------- Phase 2: cross-wave f32 reduce of 15 tiles, scatter
    __syncthreads();                    // staging regions -> exchange arena
    {
        float* Exw = Ex + wid * (NTILE * 256);
        const int ro = (lg * 4) * 16 + lr;   // C/D: row=lg*4+r, col=lr
#define PUT(IDX, ACC) { _Pragma("unroll") \
        for (int r = 0; r < 4; ++r) Exw[(IDX) * 256 + ro + r * 16] = (ACC)[r]; }
        PUT(0, g00) PUT(1, g01) PUT(2, g02) PUT(3, g03)
        PUT(4, g11) PUT(5, g12) PUT(6, g13)
        PUT(7, g22) PUT(8, g23) PUT(9, g33)
        PUT(10, am0) PUT(11, am1) PUT(12, am2) PUT(13, am3)
        PUT(14, app)
#undef PUT
    }
    __syncthreads();
    {
        const int er = t >> 4, ec = t & 15;      // entry (row, col) in a tile
        const int ti[10] = {0,0,0,0,1,1,1,2,2,3};
        const int tj[10] = {0,1,2,3,1,2,3,2,3,3};
        #pragma unroll
        for (int k = 0; k < 10; ++k) {
            float v = Ex[0 * NTILE * 256 + k * 256 + t]
                    + Ex[1 * NTILE * 256 + k * 256 + t]
                    + Ex[2 * NTILE * 256 + k * 256 + t]
                    + Ex[3 * NTILE * 256 + k * 256 + t];
            const short gv = f2bf(v);
            const int gr = ti[k] * 16 + er, gc = tj[k] * 16 + ec;
            Gs[gr * 72 + gc] = gv;
            Gs[gc * 72 + gr] = gv;      // symmetry (bitwise-equal on diagonal)
        }
        #pragma unroll
        for (int k = 0; k < 4; ++k) {
            float v = Ex[0 * NTILE * 256 + (10 + k) * 256 + t]
                    + Ex[1 * NTILE * 256 + (10 + k) * 256 + t]
                    + Ex[2 * NTILE * 256 + (10 + k) * 256 + t]
                    + Ex[3 * NTILE * 256 + (10 + k) * 256 + t];
            Ms[(k * 16 + er) * 16 + ec] = v;
        }
        {
            float v = Ex[0 * NTILE * 256 + 14 * 256 + t]
                    + Ex[1 * NTILE * 256 + 14 * 256 + t]
                    + Ex[2 * NTILE * 256 + 14 * 256 + t]
                    + Ex[3 * NTILE * 256 + 14 * 256 + t];
            if (er == 8) p0_s[ec] = v;  // row 8 of P P^T = e . P[col]
        }
    }
    __syncthreads();

    // ---------------- Phase 3 (closed form): w1 = H^T w, w2 = H^T w1, assemble
    // coefficient constants (compile-time)
    const float pM0 = (float)(-dLRS * 20.0  * dpow(dC, 19));
    const float pM1 = (float)( dLRS * dLRS * 190.0  * dpow(dC, 18));
    const float pM2 = (float)(-dLRS * dLRS * dLRS * 1140.0 * dpow(dC, 17));
    const float pY0 = (float)( dLRS * dD0());
    const float pY1 = (float)(-dLRS * dLRS * dD1());
    const float pY2 = (float)( dLRS * dLRS * dLRS * dD2());
    const float kG0 = (float)dpow(dC, 20);
    // F^20 z0 coefficients: kG0 - 20 c^19 LRS w1b + 190 c^18 LRS^2 w2b == pM0/pM1 reuse

    const int row0 = wid * 16 + lg * 4;

    // fill A: Ss[col][k] = bf16(q[k] + 1) for all 16 cols (column-broadcast)
    {
        const int ct = t & 15, k0 = (t >> 4) * 4;
        short4 sp;
        sp.x = f2bf(Ms[(k0 + 0) * 16 + 8] + 1.0f);
        sp.y = f2bf(Ms[(k0 + 1) * 16 + 8] + 1.0f);
        sp.z = f2bf(Ms[(k0 + 2) * 16 + 8] + 1.0f);
        sp.w = f2bf(Ms[(k0 + 3) * 16 + 8] + 1.0f);
        *(short4*)(&Ss[ct * 72 + k0]) = sp;
    }
    // q at this thread's rows + full sum of q (butterfly; per-wave redundant)
    const float q0 = Ms[(row0 + 0) * 16 + 8];
    const float q1 = Ms[(row0 + 1) * 16 + 8];
    const float q2 = Ms[(row0 + 2) * 16 + 8];
    const float q3 = Ms[(row0 + 3) * 16 + 8];
    float qsum = Ms[lane * 16 + 8];
    #pragma unroll
    for (int m = 1; m < 64; m <<= 1) qsum += __shfl_xor(qsum, m, 64);
    const float w1b = qsum + 64.0f;          // 1^T q + 64

    const bf16x8 ga0 = *(const bf16x8*)(&Gs[(wid * 16 + lr) * 72 +  0 + lg * 8]);
    const bf16x8 ga1 = *(const bf16x8*)(&Gs[(wid * 16 + lr) * 72 + 32 + lg * 8]);

    __syncthreads();                         // fill-A visible
    // MFMA A: w1_X = G (q + 1); rows row0..row0+3 at this lane (repl over lr)
    float w10, w11, w12, w13;
    {
        const bf16x8 sb0 = *(const bf16x8*)(&Ss[lr * 72 +  0 + lg * 8]);
        const bf16x8 sb1 = *(const bf16x8*)(&Ss[lr * 72 + 32 + lg * 8]);
        f32x4 o = {0.f, 0.f, 0.f, 0.f};
        o = MFMA16(ga0, sb0, o);
        o = MFMA16(ga1, sb1, o);
        w10 = o[0]; w11 = o[1]; w12 = o[2]; w13 = o[3];
    }
    // wave partial row-sum of w1 (count each row once: lr==0 only)
    float val = (lr == 0) ? (w10 + w11 + w12 + w13) : 0.0f;
    #pragma unroll
    for (int m = 1; m < 64; m <<= 1) val += __shfl_xor(val, m, 64);
    if (lane == 0) red[wid] = val;
    __syncthreads();                         // Ss reads done; red visible

    // fill B: t1 = w1 + w1b at own rows, col = lr (covers all 16 cols)
    {
        short4 sp;
        sp.x = f2bf(w10 + w1b); sp.y = f2bf(w11 + w1b);
        sp.z = f2bf(w12 + w1b); sp.w = f2bf(w13 + w1b);
        *(short4*)(&Ss[lr * 72 + row0]) = sp;
    }
    const float w1sum = red[0] + red[1] + red[2] + red[3];
    const float w2b = w1sum + 64.0f * w1b;   // 1^T w1_X + 64 w1b
    __syncthreads();                         // fill-B visible

    // MFMA B: w2_X = G (w1_X + w1b)
    float w20, w21, w22, w23;
    {
        const bf16x8 sb0 = *(const bf16x8*)(&Ss[lr * 72 +  0 + lg * 8]);
        const bf16x8 sb1 = *(const bf16x8*)(&Ss[lr * 72 + 32 + lg * 8]);
        f32x4 o = {0.f, 0.f, 0.f, 0.f};
        o = MFMA16(ga0, sb0, o);
        o = MFMA16(ga1, sb1, o);
        w20 = o[0]; w21 = o[1]; w22 = o[2]; w23 = o[3];
    }

    // assemble: a_k = uM(k)+cM multiplies M0 rows; y_k = uY(k)+cY scatters to label
    const float cM  = pM0 + pM1 * w1b + pM2 * w2b;
    const float cY  = pY0 + pY1 * w1b + pY2 * w2b;
    const float sb0c = kG0 + pM0 * w1b + pM1 * w2b;   // F^20 z0 b-coefficient

    float acc[8] = {0.f, 0.f, 0.f, 0.f, 0.f, 0.f, 0.f, 0.f};
    if (lr == 0) {
        const float qs[4]  = {q0, q1, q2, q3};
        const float w1s[4] = {w10, w11, w12, w13};
        const float w2s[4] = {w20, w21, w22, w23};
        #pragma unroll
        for (int r = 0; r < 4; ++r) {
            const int row = row0 + r;
            const float a = pM0 * qs[r] + pM1 * w1s[r] + pM2 * w2s[r] + cM;
            const float y = pY0 * qs[r] + pY1 * w1s[r] + pY2 * w2s[r] + cY;
            const int lab = lab_s[row];
            const float4 mlo = *(const float4*)(&Ms[row * 16 + 0]);
            const float4 mhi = *(const float4*)(&Ms[row * 16 + 4]);
            acc[0] += a * mlo.x + ((lab == 0) ? y : 0.f);
            acc[1] += a * mlo.y + ((lab == 1) ? y : 0.f);
            acc[2] += a * mlo.z + ((lab == 2) ? y : 0.f);
            acc[3] += a * mlo.w + ((lab == 3) ? y : 0.f);
            acc[4] += a * mhi.x + ((lab == 4) ? y : 0.f);
            acc[5] += a * mhi.y + ((lab == 5) ? y : 0.f);
            acc[6] += a * mhi.z + ((lab == 6) ? y : 0.f);
            acc[7] += a * mhi.w + ((lab == 7) ? y : 0.f);
        }
    }
    #pragma unroll
    for (int j = 0; j < 8; ++j) {
        #pragma unroll
        for (int m = 1; m < 64; m <<= 1) acc[j] += __shfl_xor(acc[j], m, 64);
    }
    if (lane == 0) {
        #pragma unroll
        for (int j = 0; j < 8; ++j) red[16 + wid * 8 + j] = acc[j];
    }
    __syncthreads();
    if (t < 8) {
        const float s = red[16 + 0 * 8 + t] + red[16 + 1 * 8 + t] +
                        red[16 + 2 * 8 + t] + red[16 + 3 * 8 + t];
        // thread t: lr == t -> bc = b0[t]
        out[b * LL + t] = kG0 * p0_s[t] + sb0c * bc + s;
    }
}

extern "C" void kernel_launch(void* const* d_in, const int* in_sizes, int n_in,
                              void* d_out, int out_size, void* d_ws, size_t ws_size,
                              hipStream_t stream) {
    const float* demo   = (const float*)d_in[0]; // demo_embeddings [512,64,1024]
    const float* emb    = (const float*)d_in[1]; // embeddings     [512,1024]
    const float* W0     = (const float*)d_in[2]; // W0             [512,8,1024]
    const float* b0     = (const float*)d_in[3]; // b0             [512,8]
    const int*   labels = (const int*)d_in[4];   // demo_labels    [512,64]
    float* out = (float*)d_out;                  // logits         [512,8] f32
    (void)in_sizes; (void)n_in; (void)out_size; (void)d_ws; (void)ws_size;
    hipLaunchKernelGGL(knn_linear_fix_kernel, dim3(BB), dim3(256), 0, stream,
                       demo, emb, W0, b0, labels, out);
}